// Round 3
// baseline (493.806 us; speedup 1.0000x reference)
//
#include <hip/hip_runtime.h>
#include <cstdint>

typedef __attribute__((ext_vector_type(8))) short short8;
typedef __attribute__((ext_vector_type(4))) float f32x4;

#define NB 16
#define NT 2048
#define ND 1024
#define NC 512
#define NM (NB*NT)   // 32768 rows

#define BM 64        // rows per block
#define BKS 32       // K per pipeline stage (double-buffered)
#define NSTAGE (ND/BKS)  // 32
#define NWAVE 8      // 512 threads

__device__ __forceinline__ unsigned short f2bf(float f){
  unsigned int u = __float_as_uint(f);
  u += 0x7fffu + ((u >> 16) & 1u);   // RNE; inputs are finite normals
  return (unsigned short)(u >> 16);
}

// async 16B global -> LDS DMA (wave-uniform LDS base + lane*16)
__device__ __forceinline__ void async_copy16(const void* g, void* l) {
  __builtin_amdgcn_global_load_lds(
      (const __attribute__((address_space(1))) void*)g,
      (__attribute__((address_space(3))) void*)l,
      16, 0, 0);
}

// ---------------- fused CAM GEMM + softmax + pooling partials ----------------
// Block: 512 threads (8 waves), 64 rows x full C=512. 2 blocks/CU (76 KB LDS).
// A staged from F fp32 via registers (convert to bf16 in-kernel, fuses the old
// convert_pool kernel); B staged via global_load_lds DMA. Counted vmcnt:
// uniform 5 vmem ops per wave per stage (4 B-DMA + 1 A-float4 load), so
// `s_waitcnt vmcnt(5)` == "previous stage's loads complete, current prefetch
// in flight". Raw s_barrier (no implicit drain); vmcnt never hits 0 in-loop.
//
// LDS layouts (zero read-conflict):
//  As[buf][kc][row][8]: read addr16 = kc*64+row -> lanes consecutive ✓.
//  Bs[buf]: cell(col,slot) at col*4+slot, slot = kc ^ ((col>>1)&3).
//   Read beat slots = {0,4,1,5,2,6,3,7} (distinct) -> 0 conflict.
//   DMA: linear dest; source k-chunk pre-swizzled: kc = (lane&3)^((lane>>3)&3).
// Pooling: per-stage 4x LDS atomicAdd per thread into scratch[1024]; flushed
// to part2[block][1024]; scratch then reused as redmax/redsum for softmax.
__global__ __launch_bounds__(512, 4) void cam_fused_kernel(
    const float* __restrict__ F,             // fp32 [32768,1024]
    const unsigned short* __restrict__ Wb,   // bf16 [512,1024]
    float* __restrict__ part2,               // [512][1024] pooling partials
    float* __restrict__ out_soft,
    float* __restrict__ out_raw)
{
  __shared__ alignas(16) unsigned short As[2][4][BM][8];   // 8 KB
  __shared__ alignas(16) unsigned short Bs[2][NC * BKS];   // 64 KB
  __shared__ float scratch[1024];                          // 4 KB: pool -> red

  const int tid    = threadIdx.x;
  const int wave   = tid >> 6;
  const int lane   = tid & 63;
  const int lane15 = lane & 15;
  const int quad   = lane >> 4;
  const int m0     = blockIdx.x * BM;

  // B DMA geometry (per-lane, loop-invariant)
  const int bcol_l = lane >> 2;                              // col within seg
  const int bkoff  = ((lane & 3) ^ ((lane >> 3) & 3)) * 8;   // src k-chunk
  // B fragment read slot (elems): slot = quad ^ ((col>>1)&3), col%16=lane15
  const int bslot  = (quad ^ ((lane15 >> 1) & 3)) * 8;
  // A loader geometry
  const int arow = tid >> 3;     // 0..63
  const int akq  = tid & 7;      // float4 index within 32-k row

  f32x4 acc[4][4];
  #pragma unroll
  for (int mi = 0; mi < 4; mi++)
    #pragma unroll
    for (int ni = 0; ni < 4; ni++)
      acc[mi][ni] = (f32x4){0.f, 0.f, 0.f, 0.f};

  auto stageB = [&](int t, int buf) {
    const int k0 = t * BKS;
    #pragma unroll
    for (int s = 0; s < 4; s++) {
      const int seg = wave * 4 + s;              // 32 segs of 1 KB
      async_copy16(Wb + (size_t)(seg * 16 + bcol_l) * ND + k0 + bkoff,
                   &Bs[buf][seg * 512]);
    }
  };
  auto loadA = [&](int t) -> float4 {
    return *reinterpret_cast<const float4*>(
        F + (size_t)(m0 + arow) * ND + t * BKS + akq * 4);
  };
  auto writeA = [&](int buf, float4 v) {
    ushort4 s4;
    s4.x = f2bf(v.x); s4.y = f2bf(v.y); s4.z = f2bf(v.z); s4.w = f2bf(v.w);
    *reinterpret_cast<ushort4*>(&As[buf][akq >> 1][arow][(akq & 1) * 4]) = s4;
  };
  auto pool = [&](int t, float4 v) {
    const int base = t * BKS + akq * 4;
    atomicAdd(&scratch[base + 0], v.x);
    atomicAdd(&scratch[base + 1], v.y);
    atomicAdd(&scratch[base + 2], v.z);
    atomicAdd(&scratch[base + 3], v.w);
  };
  auto compute = [&](int buf) {
    short8 af[4];
    #pragma unroll
    for (int mi = 0; mi < 4; mi++)
      af[mi] = *reinterpret_cast<const short8*>(
          &As[buf][quad][mi * 16 + lane15][0]);
    #pragma unroll
    for (int ni = 0; ni < 4; ni++) {
      const int col = wave * 64 + ni * 16 + lane15;
      const short8 bf = *reinterpret_cast<const short8*>(
          &Bs[buf][col * 32 + bslot]);
      #pragma unroll
      for (int mi = 0; mi < 4; mi++)
        acc[mi][ni] = __builtin_amdgcn_mfma_f32_16x16x32_bf16(
            af[mi], bf, acc[mi][ni], 0, 0, 0);
    }
  };

  // zero pooling accumulator
  scratch[tid] = 0.f;
  scratch[tid + 512] = 0.f;

  // ---- prologue: tiles 0,1 in flight ----
  stageB(0, 0); float4 av0 = loadA(0);
  stageB(1, 1); float4 av1 = loadA(1);
  __builtin_amdgcn_s_barrier();                       // zeros visible
  asm volatile("s_waitcnt vmcnt(5)" ::: "memory");    // B(0)+A(0) done
  writeA(0, av0); pool(0, av0);
  __builtin_amdgcn_s_barrier();                       // tile0 ready

  #pragma unroll 1
  for (int t = 0; t < NSTAGE; t += 2) {
    // ---- phase A: compute tile t (buf0); B(t+1)/A(t+1) in flight ----
    __builtin_amdgcn_s_setprio(1);
    compute(0);
    __builtin_amdgcn_s_setprio(0);
    __builtin_amdgcn_s_barrier();            // all waves done reading buf0
    if (t + 2 < NSTAGE) {
      stageB(t + 2, 0); av0 = loadA(t + 2);  // +5 in flight
      asm volatile("s_waitcnt vmcnt(5)" ::: "memory");  // B(t+1)+A(t+1) done
    } else {
      asm volatile("s_waitcnt vmcnt(0)" ::: "memory");
    }
    writeA(1, av1); pool(t + 1, av1);
    __builtin_amdgcn_s_barrier();            // tile t+1 fully in LDS

    // ---- phase B: compute tile t+1 (buf1); B(t+2)/A(t+2) in flight ----
    __builtin_amdgcn_s_setprio(1);
    compute(1);
    __builtin_amdgcn_s_setprio(0);
    __builtin_amdgcn_s_barrier();            // all waves done reading buf1
    if (t + 3 < NSTAGE) {
      stageB(t + 3, 1); av1 = loadA(t + 3);
      asm volatile("s_waitcnt vmcnt(5)" ::: "memory");  // B(t+2)+A(t+2) done
      writeA(0, av0); pool(t + 2, av0);
    }
    __builtin_amdgcn_s_barrier();            // tile t+2 fully in LDS
  }

  // ---- flush pooling partials ----
  part2[(size_t)blockIdx.x * ND + tid]       = scratch[tid];
  part2[(size_t)blockIdx.x * ND + tid + 512] = scratch[tid + 512];
  __syncthreads();                           // scratch reusable as red arrays
  float* redmax_s = scratch;        // [8][64]
  float* redsum_s = scratch + 512;  // [8][64]

  // ---- epilogue: fused softmax over C=512 ----
  // C/D layout: col = lane15 (+wave*64+ni*16), row = quad*4 + reg (+mi*16)
  #pragma unroll
  for (int mi = 0; mi < 4; mi++)
    #pragma unroll
    for (int r = 0; r < 4; r++) {
      float m = acc[mi][0][r];
      #pragma unroll
      for (int ni = 1; ni < 4; ni++) m = fmaxf(m, acc[mi][ni][r]);
      #pragma unroll
      for (int off = 1; off < 16; off <<= 1) m = fmaxf(m, __shfl_xor(m, off, 64));
      if (lane15 == 0) redmax_s[wave * 64 + mi * 16 + quad * 4 + r] = m;
    }
  __syncthreads();

  float rsum[4][4];
  #pragma unroll
  for (int mi = 0; mi < 4; mi++)
    #pragma unroll
    for (int r = 0; r < 4; r++) {
      const int row = mi * 16 + quad * 4 + r;
      float m = redmax_s[row];
      #pragma unroll
      for (int w = 1; w < NWAVE; w++) m = fmaxf(m, redmax_s[w * 64 + row]);
      float s = 0.f;
      #pragma unroll
      for (int ni = 0; ni < 4; ni++) {
        const float e = __expf(acc[mi][ni][r] - m);
        acc[mi][ni][r] = e;
        s += e;
      }
      #pragma unroll
      for (int off = 1; off < 16; off <<= 1) s += __shfl_xor(s, off, 64);
      rsum[mi][r] = s;
    }
  if (lane15 == 0) {
    #pragma unroll
    for (int mi = 0; mi < 4; mi++)
      #pragma unroll
      for (int r = 0; r < 4; r++)
        redsum_s[wave * 64 + mi * 16 + quad * 4 + r] = rsum[mi][r];
  }
  __syncthreads();

  #pragma unroll
  for (int mi = 0; mi < 4; mi++)
    #pragma unroll
    for (int r = 0; r < 4; r++) {
      const int row = mi * 16 + quad * 4 + r;
      float s = redsum_s[row];
      #pragma unroll
      for (int w = 1; w < NWAVE; w++) s += redsum_s[w * 64 + row];
      const float inv = 1.f / s;
      const size_t gr = (size_t)(m0 + row) * NC;
      #pragma unroll
      for (int ni = 0; ni < 4; ni++) {
        const int col = wave * 64 + ni * 16 + lane15;
        const float v = acc[mi][ni][r] * inv;
        out_soft[gr + col] = v;
        out_raw [gr + col] = v;
      }
    }
}

// ---------------- W fp32 -> bf16 ----------------
__global__ __launch_bounds__(256) void convw_kernel(
    const float* __restrict__ W, unsigned short* __restrict__ Wb)
{
  const size_t j = ((size_t)blockIdx.x * 256 + threadIdx.x) * 8;
  const float4 a = *reinterpret_cast<const float4*>(W + j);
  const float4 c = *reinterpret_cast<const float4*>(W + j + 4);
  ushort4 lo, hi;
  lo.x = f2bf(a.x); lo.y = f2bf(a.y); lo.z = f2bf(a.z); lo.w = f2bf(a.w);
  hi.x = f2bf(c.x); hi.y = f2bf(c.y); hi.z = f2bf(c.z); hi.w = f2bf(c.w);
  *reinterpret_cast<ushort4*>(Wb + j) = lo;
  *reinterpret_cast<ushort4*>(Wb + j + 4) = hi;
}

// ---------------- logits = pooled @ W^T + b (fp32) ----------------
__global__ __launch_bounds__(512) void logits_kernel(
    const float* __restrict__ part2, const float* __restrict__ W,
    const float* __restrict__ bias, float* __restrict__ out_logits)
{
  __shared__ float p[ND];
  const int b = blockIdx.x;
  const int tid = threadIdx.x;
  for (int i = tid; i < ND; i += 512) {
    float s = 0.f;
    #pragma unroll
    for (int z = 0; z < 32; z++)
      s += part2[(size_t)(b * 32 + z) * ND + i];
    p[i] = s * (1.f / NT);
  }
  __syncthreads();
  const int c = tid;
  const float* wr = W + (size_t)c * ND;
  float s = 0.f;
  for (int k = 0; k < ND; k++) s = fmaf(p[k], wr[k], s);
  out_logits[b * NC + c] = s + bias[c];
}

// ---------------- cross-entropy loss (fp32) ----------------
__global__ __launch_bounds__(512) void loss_kernel(
    const float* __restrict__ logits, const int* __restrict__ labels,
    float* __restrict__ out_loss)
{
  __shared__ float red[8];
  const int tid = threadIdx.x;
  float acc = 0.f;
  for (int b = 0; b < NB; b++) {
    const float v = logits[b * NC + tid];
    float m = v;
    #pragma unroll
    for (int off = 32; off; off >>= 1) m = fmaxf(m, __shfl_xor(m, off, 64));
    if ((tid & 63) == 0) red[tid >> 6] = m;
    __syncthreads();
    m = red[0];
    #pragma unroll
    for (int w = 1; w < 8; w++) m = fmaxf(m, red[w]);
    __syncthreads();
    float e = expf(v - m);
    #pragma unroll
    for (int off = 32; off; off >>= 1) e += __shfl_xor(e, off, 64);
    if ((tid & 63) == 0) red[tid >> 6] = e;
    __syncthreads();
    if (tid == 0) {
      float s = red[0] + red[1] + red[2] + red[3] + red[4] + red[5] + red[6] + red[7];
      const int lab = labels[b];
      acc += -(logits[b * NC + lab] - m - logf(s));
    }
    __syncthreads();
  }
  if (tid == 0) out_loss[0] = acc * (1.f / NB);
}

extern "C" void kernel_launch(void* const* d_in, const int* in_sizes, int n_in,
                              void* d_out, int out_size, void* d_ws, size_t ws_size,
                              hipStream_t stream) {
  const float* F      = (const float*)d_in[0];   // [16,2048,1024]
  const int*   labels = (const int*)  d_in[1];   // [16]
  const float* W      = (const float*)d_in[2];   // [512,1024]
  const float* bias   = (const float*)d_in[3];   // [512]

  float* out        = (float*)d_out;
  float* out_soft   = out;
  float* out_raw    = out + (size_t)NM * NC;
  float* out_logits = out + (size_t)2 * NM * NC;
  float* out_loss   = out_logits + (size_t)NB * NC;

  // ws layout: part2 [0, 2 MiB) | Wb [2 MiB, 3 MiB)
  char* ws = (char*)d_ws;
  float* part2 = (float*)ws;                                    // 512*1024 f32
  unsigned short* Wb = (unsigned short*)(ws + (2u << 20));      // 512*1024 bf16

  convw_kernel<<<NC * ND / (256 * 8), 256, 0, stream>>>(W, Wb);
  cam_fused_kernel<<<NM / BM, 512, 0, stream>>>(F, Wb, part2, out_soft, out_raw);
  logits_kernel<<<NB, 512, 0, stream>>>(part2, W, bias, out_logits);
  loss_kernel<<<1, 512, 0, stream>>>(out_logits, labels, out_loss);
}

// Round 4
// 382.936 us; speedup vs baseline: 1.2895x; 1.2895x over previous
//
#include <hip/hip_runtime.h>
#include <cstdint>

typedef __attribute__((ext_vector_type(8))) short short8;
typedef __attribute__((ext_vector_type(4))) float f32x4;

#define NB 16
#define NT 2048
#define ND 1024
#define NC 512
#define NM (NB*NT)   // 32768 rows

#define BM 64        // rows per block
#define BKS 32       // K per pipeline stage (double-buffered)
#define NSTAGE (ND/BKS)  // 32
#define NWAVE 8      // 512 threads

__device__ __forceinline__ unsigned short f2bf(float f){
  unsigned int u = __float_as_uint(f);
  u += 0x7fffu + ((u >> 16) & 1u);   // RNE; inputs are finite normals
  return (unsigned short)(u >> 16);
}

// async 16B global -> LDS DMA (wave-uniform LDS base + lane*16)
__device__ __forceinline__ void async_copy16(const void* g, void* l) {
  __builtin_amdgcn_global_load_lds(
      (const __attribute__((address_space(1))) void*)g,
      (__attribute__((address_space(3))) void*)l,
      16, 0, 0);
}

// ---------------- CAM GEMM + fused softmax ----------------
// Block: 512 threads (8 waves), 64 rows x full C=512 (softmax in-block).
// 74 KB LDS -> 2 blocks/CU (the round-2 regression was losing this).
//
// COUNTED-VMCNT PIPELINE (T4), per-wave-uniform DMA counts:
//   every wave: 4 B-seg DMAs/stage; waves 0-3 additionally 1 A-seg DMA.
//   -> waves 0-3 wait vmcnt(5), waves 4-7 wait vmcnt(4): previous tile
//   complete, current prefetch stays in flight. Raw s_barrier only; vmcnt
//   never drains to 0 inside the main loop (the round-0/1 stall was the
//   implicit vmcnt(0)+lgkmcnt(0) drain at every __syncthreads()).
//
// LDS layouts:
//  As[buf] elem = row*32 + k (linear; DMA source linear; read units distinct).
//  Bs[buf]: cell(col, slot) at elem col*32 + slot*8, slot = kc ^ ((col>>1)&3)
//   (kc = 16B k-chunk). DMA: linear dest, source k-chunk pre-swizzled
//   kc_src = (lane&3) ^ ((lane>>3)&3); read slot = quad ^ ((lane15>>1)&3).
//   (harness-verified in round 3; cut SQ_LDS_BANK_CONFLICT 4.19M -> 1.57M)
template<bool PRECONV>
__global__ __launch_bounds__(512, 4) void cam_softmax_kernel(
    const unsigned short* __restrict__ Fb,   // bf16 [32768,1024] (PRECONV)
    const float* __restrict__ F,             // fp32 [32768,1024] (!PRECONV)
    const unsigned short* __restrict__ Wb,   // bf16 [512,1024]
    float* __restrict__ out_soft,
    float* __restrict__ out_raw)
{
  __shared__ alignas(16) unsigned short As[2][BM * BKS];    // 2 x 4 KB
  __shared__ alignas(16) unsigned short Bs[2][NC * BKS];    // 2 x 32 KB
  __shared__ float redmax[NWAVE][BM];
  __shared__ float redsum[NWAVE][BM];

  const int tid    = threadIdx.x;
  const int wave   = tid >> 6;
  const int lane   = tid & 63;
  const int lane15 = lane & 15;
  const int quad   = lane >> 4;
  const int m0     = blockIdx.x * BM;

  // staging geometry (per-lane, loop-invariant)
  const int rr     = lane >> 2;                              // row within seg
  const int bkoff  = ((lane & 3) ^ ((lane >> 3) & 3)) * 8;   // B src k-chunk
  const int akoff  = (lane & 3) * 8;                         // A src (linear)
  // B fragment read slot (elems): slot = quad ^ ((col>>1)&3), col%16 = lane15
  const int bslot  = (quad ^ ((lane15 >> 1) & 3)) * 8;

  f32x4 acc[4][4];
  #pragma unroll
  for (int mi = 0; mi < 4; mi++)
    #pragma unroll
    for (int ni = 0; ni < 4; ni++)
      acc[mi][ni] = (f32x4){0.f, 0.f, 0.f, 0.f};

  auto stageB = [&](int t, int buf) {
    const int k0 = t * BKS;
    #pragma unroll
    for (int s = 0; s < 4; s++) {
      const int seg = wave * 4 + s;                // 32 segs of 1 KB
      async_copy16(Wb + (size_t)(seg * 16 + rr) * ND + k0 + bkoff,
                   &Bs[buf][seg * 512]);
    }
  };
  auto stageA = [&](int t, int buf) {
    if (wave < 4) {                                // 4 segs of 1 KB
      async_copy16(Fb + (size_t)(m0 + wave * 16 + rr) * ND + t * BKS + akoff,
                   &As[buf][wave * 512]);
    }
  };
  auto waitprev = [&]() {
    if (wave < 4) asm volatile("s_waitcnt vmcnt(5)" ::: "memory");
    else          asm volatile("s_waitcnt vmcnt(4)" ::: "memory");
  };
  auto compute = [&](int buf) {
    short8 af[4];
    #pragma unroll
    for (int mi = 0; mi < 4; mi++)
      af[mi] = *reinterpret_cast<const short8*>(
          &As[buf][(mi * 16 + lane15) * 32 + quad * 8]);
    #pragma unroll
    for (int ni = 0; ni < 4; ni++) {
      const int col = wave * 64 + ni * 16 + lane15;
      const short8 bf = *reinterpret_cast<const short8*>(
          &Bs[buf][col * 32 + bslot]);
      #pragma unroll
      for (int mi = 0; mi < 4; mi++)
        acc[mi][ni] = __builtin_amdgcn_mfma_f32_16x16x32_bf16(
            af[mi], bf, acc[mi][ni], 0, 0, 0);
    }
  };

  if (PRECONV) {
    // ---- prologue: tiles 0,1 in flight; wait tile 0 only ----
    stageB(0, 0); stageA(0, 0);
    stageB(1, 1); stageA(1, 1);
    waitprev();
    __builtin_amdgcn_s_barrier();

    #pragma unroll 1
    for (int t = 0; t < NSTAGE; t += 2) {
      // ---- phase A: compute tile t (buf0); tile t+1 in flight ----
      __builtin_amdgcn_s_setprio(1);
      compute(0);
      __builtin_amdgcn_s_setprio(0);
      __builtin_amdgcn_s_barrier();          // all waves done reading buf0
      if (t + 2 < NSTAGE) {
        stageB(t + 2, 0); stageA(t + 2, 0);  // keep pipe full
        waitprev();                          // tile t+1 complete
      } else {
        asm volatile("s_waitcnt vmcnt(0)" ::: "memory");
      }
      __builtin_amdgcn_s_barrier();          // tile t+1 visible to all waves

      // ---- phase B: compute tile t+1 (buf1); tile t+2 in flight ----
      __builtin_amdgcn_s_setprio(1);
      compute(1);
      __builtin_amdgcn_s_setprio(0);
      __builtin_amdgcn_s_barrier();          // all waves done reading buf1
      if (t + 3 < NSTAGE) {
        stageB(t + 3, 1); stageA(t + 3, 1);
        waitprev();                          // tile t+2 complete
      } else {
        asm volatile("s_waitcnt vmcnt(0)" ::: "memory");
      }
      __builtin_amdgcn_s_barrier();
    }
  } else {
    // ---- fallback (F fp32 direct): simple drain loop, single set ----
    for (int ks = 0; ks < NSTAGE; ks++) {
      stageB(ks, 0);
      {
        const int row = tid >> 3;
        const int kq  = tid & 7;             // float4 index in 32-k row
        const float4 v = *reinterpret_cast<const float4*>(
            F + (size_t)(m0 + row) * ND + ks * BKS + kq * 4);
        ushort4 s4;
        s4.x = f2bf(v.x); s4.y = f2bf(v.y); s4.z = f2bf(v.z); s4.w = f2bf(v.w);
        *reinterpret_cast<ushort4*>(&As[0][row * 32 + kq * 4]) = s4;
      }
      __syncthreads();
      compute(0);
      __syncthreads();
    }
  }

  // ---- epilogue: fused softmax over C=512 ----
  // C/D layout: col = lane15 (+wave*64+ni*16), row = quad*4 + reg (+mi*16)
  #pragma unroll
  for (int mi = 0; mi < 4; mi++)
    #pragma unroll
    for (int r = 0; r < 4; r++) {
      float m = acc[mi][0][r];
      #pragma unroll
      for (int ni = 1; ni < 4; ni++) m = fmaxf(m, acc[mi][ni][r]);
      #pragma unroll
      for (int off = 1; off < 16; off <<= 1) m = fmaxf(m, __shfl_xor(m, off, 64));
      if (lane15 == 0) redmax[wave][mi * 16 + quad * 4 + r] = m;
    }
  __syncthreads();

  float rsum[4][4];
  #pragma unroll
  for (int mi = 0; mi < 4; mi++)
    #pragma unroll
    for (int r = 0; r < 4; r++) {
      const int row = mi * 16 + quad * 4 + r;
      float m = redmax[0][row];
      #pragma unroll
      for (int w = 1; w < NWAVE; w++) m = fmaxf(m, redmax[w][row]);
      float s = 0.f;
      #pragma unroll
      for (int ni = 0; ni < 4; ni++) {
        const float e = __expf(acc[mi][ni][r] - m);
        acc[mi][ni][r] = e;
        s += e;
      }
      #pragma unroll
      for (int off = 1; off < 16; off <<= 1) s += __shfl_xor(s, off, 64);
      rsum[mi][r] = s;
    }
  if (lane15 == 0) {
    #pragma unroll
    for (int mi = 0; mi < 4; mi++)
      #pragma unroll
      for (int r = 0; r < 4; r++)
        redsum[wave][mi * 16 + quad * 4 + r] = rsum[mi][r];
  }
  __syncthreads();

  #pragma unroll
  for (int mi = 0; mi < 4; mi++)
    #pragma unroll
    for (int r = 0; r < 4; r++) {
      const int row = mi * 16 + quad * 4 + r;
      float s = redsum[0][row];
      #pragma unroll
      for (int w = 1; w < NWAVE; w++) s += redsum[w][row];
      const float inv = 1.f / s;
      const size_t gr = (size_t)(m0 + row) * NC;
      #pragma unroll
      for (int ni = 0; ni < 4; ni++) {
        const int col = wave * 64 + ni * 16 + lane15;
        const float v = acc[mi][ni][r] * inv;
        out_soft[gr + col] = v;
        out_raw [gr + col] = v;
      }
    }
}

// ---------------- fused convert(+pool): F fp32 -> Fb bf16, partial sums over T ----------------
// grid (32 zchunks, 16 b), 512 threads: tid covers (thalf = tid>>8, d-quad = tid&255)
template<bool WRITE_FB>
__global__ __launch_bounds__(512) void convert_pool_kernel(
    const float* __restrict__ F, unsigned short* __restrict__ Fb,
    float* __restrict__ part)    // part[32][16][1024]
{
  __shared__ float4 psum[512];
  const int tid = threadIdx.x;
  const int z = blockIdx.x;
  const int b = blockIdx.y;
  const int th = tid >> 8;              // 0/1
  const int d4 = (tid & 255) * 4;

  float4 s = (float4){0.f, 0.f, 0.f, 0.f};
  const size_t base = ((size_t)b * NT + z * 64) * ND;
  #pragma unroll 4
  for (int t = th; t < 64; t += 2) {
    const size_t idx = base + (size_t)t * ND + d4;
    const float4 v = *reinterpret_cast<const float4*>(F + idx);
    if (WRITE_FB) {
      ushort4 s4;
      s4.x = f2bf(v.x); s4.y = f2bf(v.y); s4.z = f2bf(v.z); s4.w = f2bf(v.w);
      *reinterpret_cast<ushort4*>(Fb + idx) = s4;
    }
    s.x += v.x; s.y += v.y; s.z += v.z; s.w += v.w;
  }
  psum[tid] = s;
  __syncthreads();
  if (tid < 256) {
    const float4 a = psum[tid];
    const float4 c = psum[tid + 256];
    float4 r;
    r.x = a.x + c.x; r.y = a.y + c.y; r.z = a.z + c.z; r.w = a.w + c.w;
    *reinterpret_cast<float4*>(part + (size_t)(z * NB + b) * ND + d4) = r;
  }
}

// ---------------- W fp32 -> bf16 ----------------
__global__ __launch_bounds__(256) void convw_kernel(
    const float* __restrict__ W, unsigned short* __restrict__ Wb)
{
  const size_t j = ((size_t)blockIdx.x * 256 + threadIdx.x) * 8;
  const float4 a = *reinterpret_cast<const float4*>(W + j);
  const float4 c = *reinterpret_cast<const float4*>(W + j + 4);
  ushort4 lo, hi;
  lo.x = f2bf(a.x); lo.y = f2bf(a.y); lo.z = f2bf(a.z); lo.w = f2bf(a.w);
  hi.x = f2bf(c.x); hi.y = f2bf(c.y); hi.z = f2bf(c.z); hi.w = f2bf(c.w);
  *reinterpret_cast<ushort4*>(Wb + j) = lo;
  *reinterpret_cast<ushort4*>(Wb + j + 4) = hi;
}

// ---------------- logits = pooled @ W^T + b (fp32) ----------------
__global__ __launch_bounds__(512) void logits_kernel(
    const float* __restrict__ part, const float* __restrict__ W,
    const float* __restrict__ bias, float* __restrict__ out_logits)
{
  __shared__ float p[ND];
  const int b = blockIdx.x;
  const int tid = threadIdx.x;
  for (int i = tid; i < ND; i += 512) {
    float s = 0.f;
    #pragma unroll
    for (int z = 0; z < 32; z++) s += part[(size_t)(z * NB + b) * ND + i];
    p[i] = s * (1.f / NT);
  }
  __syncthreads();
  const int c = tid;
  const float* wr = W + (size_t)c * ND;
  float s = 0.f;
  for (int k = 0; k < ND; k++) s = fmaf(p[k], wr[k], s);
  out_logits[b * NC + c] = s + bias[c];
}

// ---------------- cross-entropy loss (fp32) ----------------
__global__ __launch_bounds__(512) void loss_kernel(
    const float* __restrict__ logits, const int* __restrict__ labels,
    float* __restrict__ out_loss)
{
  __shared__ float red[8];
  const int tid = threadIdx.x;
  float acc = 0.f;
  for (int b = 0; b < NB; b++) {
    const float v = logits[b * NC + tid];
    float m = v;
    #pragma unroll
    for (int off = 32; off; off >>= 1) m = fmaxf(m, __shfl_xor(m, off, 64));
    if ((tid & 63) == 0) red[tid >> 6] = m;
    __syncthreads();
    m = red[0];
    #pragma unroll
    for (int w = 1; w < 8; w++) m = fmaxf(m, red[w]);
    __syncthreads();
    float e = expf(v - m);
    #pragma unroll
    for (int off = 32; off; off >>= 1) e += __shfl_xor(e, off, 64);
    if ((tid & 63) == 0) red[tid >> 6] = e;
    __syncthreads();
    if (tid == 0) {
      float s = red[0] + red[1] + red[2] + red[3] + red[4] + red[5] + red[6] + red[7];
      const int lab = labels[b];
      acc += -(logits[b * NC + lab] - m - logf(s));
    }
    __syncthreads();
  }
  if (tid == 0) out_loss[0] = acc * (1.f / NB);
}

extern "C" void kernel_launch(void* const* d_in, const int* in_sizes, int n_in,
                              void* d_out, int out_size, void* d_ws, size_t ws_size,
                              hipStream_t stream) {
  const float* F      = (const float*)d_in[0];   // [16,2048,1024]
  const int*   labels = (const int*)  d_in[1];   // [16]
  const float* W      = (const float*)d_in[2];   // [512,1024]
  const float* bias   = (const float*)d_in[3];   // [512]

  float* out        = (float*)d_out;
  float* out_soft   = out;
  float* out_raw    = out + (size_t)NM * NC;
  float* out_logits = out + (size_t)2 * NM * NC;
  float* out_loss   = out_logits + (size_t)NB * NC;

  // ws layout: part [0, 2 MiB) | Wb [2 MiB, 3 MiB) | Fb [4 MiB, 68 MiB)
  char* ws = (char*)d_ws;
  float* part = (float*)ws;                                     // 32*16*1024 f32
  unsigned short* Wb = (unsigned short*)(ws + (2u << 20));      // 512*1024 bf16
  unsigned short* Fb = (unsigned short*)(ws + (4u << 20));      // 32768*1024 bf16
  const bool preconv = ws_size >= (4u << 20) + (size_t)NM * ND * 2;

  if (preconv) {
    convert_pool_kernel<true><<<dim3(32, NB), 512, 0, stream>>>(F, Fb, part);
    convw_kernel<<<NC * ND / (256 * 8), 256, 0, stream>>>(W, Wb);
    cam_softmax_kernel<true><<<NM / BM, 512, 0, stream>>>(Fb, F, Wb, out_soft, out_raw);
  } else {
    convert_pool_kernel<false><<<dim3(32, NB), 512, 0, stream>>>(F, Fb, part);
    convw_kernel<<<NC * ND / (256 * 8), 256, 0, stream>>>(W, Wb);
    cam_softmax_kernel<false><<<NM / BM, 512, 0, stream>>>(Fb, F, Wb, out_soft, out_raw);
  }
  logits_kernel<<<NB, 512, 0, stream>>>(part, W, bias, out_logits);
  loss_kernel<<<1, 512, 0, stream>>>(out_logits, labels, out_loss);
}